// Round 2
// baseline (777.423 us; speedup 1.0000x reference)
//
#include <hip/hip_runtime.h>

#define TS 64
#define KS 16

__device__ __forceinline__ float lrelu(float v) { return v >= 0.f ? v : 0.01f * v; }

// ---------------------------------------------------------------------------
// C[i][j] = sum_k A[i][k] * B[k][j]   (all row-major, M x K, K x N)
// grid: (N/TS, M/TS), block 256
// ---------------------------------------------------------------------------
__global__ __launch_bounds__(256) void k_gemm_nn(const float* __restrict__ A,
                                                 const float* __restrict__ B,
                                                 float* __restrict__ C,
                                                 int M, int N, int K) {
    __shared__ float As[TS][KS + 1];  // As[i][k] padded
    __shared__ float Bs[KS][TS];      // Bs[k][j]
    int tid = threadIdx.x;
    int tx = tid & 15, ty = tid >> 4;
    int i0 = blockIdx.y * TS, j0 = blockIdx.x * TS;
    float acc[4][4] = {};
    for (int k0 = 0; k0 < K; k0 += KS) {
        {
            int c = tid & 15, r0 = tid >> 4;
#pragma unroll
            for (int l = 0; l < 4; ++l) {
                int r = r0 + l * 16;
                As[r][c] = A[(i0 + r) * K + k0 + c];
            }
        }
        {
            int j = tid & 63, r0 = tid >> 6;
#pragma unroll
            for (int l = 0; l < 4; ++l) {
                int r = r0 + l * 4;
                Bs[r][j] = B[(k0 + r) * N + j0 + j];
            }
        }
        __syncthreads();
#pragma unroll
        for (int kk = 0; kk < KS; ++kk) {
            float4 b4 = *(const float4*)&Bs[kk][tx * 4];
#pragma unroll
            for (int i = 0; i < 4; ++i) {
                float a = As[ty * 4 + i][kk];
                acc[i][0] += a * b4.x; acc[i][1] += a * b4.y;
                acc[i][2] += a * b4.z; acc[i][3] += a * b4.w;
            }
        }
        __syncthreads();
    }
#pragma unroll
    for (int i = 0; i < 4; ++i) {
        float4 v = {acc[i][0], acc[i][1], acc[i][2], acc[i][3]};
        *(float4*)&C[(i0 + ty * 4 + i) * N + j0 + tx * 4] = v;
    }
}

// ---------------------------------------------------------------------------
// Stage A: Out[b][t][k][o] = sum_c Wmat[o][c] * In_k[b][c][t]
// grid: (B*T/TS, C/TS, 9)  z = wsel*3 + kin ; block 256
// ---------------------------------------------------------------------------
__global__ __launch_bounds__(256) void k_stageA(
    const float* __restrict__ out1, const float* __restrict__ out2,
    const float* __restrict__ out3, const float* __restrict__ theta_w,
    const float* __restrict__ phi_w, const float* __restrict__ wg_w,
    float* __restrict__ Th, float* __restrict__ Ph, float* __restrict__ Wg) {
    const int Cc = 512, T = 128;
    int wsel = blockIdx.z / 3, kin = blockIdx.z % 3;
    const float* W = (wsel == 0) ? theta_w : ((wsel == 1) ? phi_w : wg_w);
    const float* In = (kin == 0) ? out1 : ((kin == 1) ? out2 : out3);
    float* Out = (wsel == 0) ? Th : ((wsel == 1) ? Ph : Wg);

    int col0 = blockIdx.x * TS;
    int b = col0 >> 7, t0 = col0 & 127;
    int o0 = blockIdx.y * TS;

    __shared__ float As[TS][KS + 1];  // As[o][k]
    __shared__ float Bs[KS][TS];      // Bs[k][t]
    int tid = threadIdx.x;
    int tx = tid & 15, ty = tid >> 4;
    float acc[4][4] = {};  // [i=o][j=t]

    for (int k0 = 0; k0 < 512; k0 += KS) {
        {
            int c = tid & 15, r0 = tid >> 4;
#pragma unroll
            for (int l = 0; l < 4; ++l) {
                int r = r0 + l * 16;
                As[r][c] = W[(o0 + r) * Cc + k0 + c];
            }
        }
        {
            int j = tid & 63, r0 = tid >> 6;
#pragma unroll
            for (int l = 0; l < 4; ++l) {
                int r = r0 + l * 4;
                Bs[r][j] = In[(b * Cc + k0 + r) * T + t0 + j];
            }
        }
        __syncthreads();
#pragma unroll
        for (int kk = 0; kk < KS; ++kk) {
            float4 b4 = *(const float4*)&Bs[kk][tx * 4];
#pragma unroll
            for (int i = 0; i < 4; ++i) {
                float a = As[ty * 4 + i][kk];
                acc[i][0] += a * b4.x; acc[i][1] += a * b4.y;
                acc[i][2] += a * b4.z; acc[i][3] += a * b4.w;
            }
        }
        __syncthreads();
    }
#pragma unroll
    for (int jj = 0; jj < 4; ++jj) {
        int t = t0 + tx * 4 + jj;
        float4 v = {acc[0][jj], acc[1][jj], acc[2][jj], acc[3][jj]};
        *(float4*)&Out[(((b * T + t) * 3 + kin) << 9) + o0 + ty * 4] = v;
    }
}

// ---------------------------------------------------------------------------
// Band-gram as full 128x128 gram per (b, k, k'):
// D[mat][t1][t2] = sum_o Th[b][t1][k][o] * Ph[b][t2][k'][o], mat = (b*3+k)*3+k'
// grid: (2, 2, 144), block 256 (64x64 output tile per block)
// ---------------------------------------------------------------------------
__global__ __launch_bounds__(256) void k_gram(const float* __restrict__ Th,
                                              const float* __restrict__ Ph,
                                              float* __restrict__ D) {
    int mat = blockIdx.z;
    int b = mat / 9, kk9 = mat % 9, k = kk9 / 3, kp = kk9 % 3;
    const float* A0 = Th + (b * 128 * 3 + k) * 512;   // row t1: + t1*1536
    const float* B0 = Ph + (b * 128 * 3 + kp) * 512;  // row t2: + t2*1536

    int i0 = blockIdx.y * TS, j0 = blockIdx.x * TS;
    __shared__ float As[TS][KS + 1];
    __shared__ float Bs[TS][KS + 1];
    int tid = threadIdx.x;
    int tx = tid & 15, ty = tid >> 4;
    float acc[4][4] = {};
    for (int k0 = 0; k0 < 512; k0 += KS) {
        int c = tid & 15, r0 = tid >> 4;
#pragma unroll
        for (int l = 0; l < 4; ++l) {
            int r = r0 + l * 16;
            As[r][c] = A0[(i0 + r) * 1536 + k0 + c];
            Bs[r][c] = B0[(j0 + r) * 1536 + k0 + c];
        }
        __syncthreads();
#pragma unroll
        for (int kk = 0; kk < KS; ++kk) {
            float a[4], bv[4];
#pragma unroll
            for (int i = 0; i < 4; ++i) a[i] = As[ty * 4 + i][kk];
#pragma unroll
            for (int j = 0; j < 4; ++j) bv[j] = Bs[tx * 4 + j][kk];
#pragma unroll
            for (int i = 0; i < 4; ++i)
#pragma unroll
                for (int j = 0; j < 4; ++j) acc[i][j] += a[i] * bv[j];
        }
        __syncthreads();
    }
#pragma unroll
    for (int i = 0; i < 4; ++i) {
        float4 v = {acc[i][0], acc[i][1], acc[i][2], acc[i][3]};
        *(float4*)&D[(mat * 128 + i0 + ty * 4 + i) * 128 + j0 + tx * 4] = v;
    }
}

// ---------------------------------------------------------------------------
// Mix: per (b,t): gather f (24x24) from D, softmax rows, then
// pooled[o] = max_n ( sum_m P[n][m]*WG_win[o][m] + W_b[o] + X_win[o][n] )
// grid: 2048 (b*128+t), block 128 (each thread owns 4 consecutive o)
// ---------------------------------------------------------------------------
__global__ __launch_bounds__(128) void k_mix(
    const float* __restrict__ out1, const float* __restrict__ out2,
    const float* __restrict__ out3, const float* __restrict__ Wg,
    const float* __restrict__ D, const float* __restrict__ W_b,
    float* __restrict__ Pl) {
    int bid = blockIdx.x;
    int b = bid >> 7, t = bid & 127;
    int tid = threadIdx.x;

    __shared__ float f[24][28];

    // gather f from D (zeros where window hangs off the front)
    for (int idx = tid; idx < 576; idx += 128) {
        int n = idx / 24, m = idx - n * 24;
        int j = n / 3, k = n - j * 3;
        int jp = m / 3, kp = m - jp * 3;
        int t1 = t - 7 + j, t2 = t - 7 + jp;
        float v = 0.f;
        if (t1 >= 0 && t2 >= 0)
            v = D[((((b * 3 + k) * 3 + kp) * 128 + t1) << 7) + t2];
        f[n][m] = v;
    }
    __syncthreads();

    // softmax rows
    if (tid < 24) {
        float mx = -1e30f;
#pragma unroll
        for (int m = 0; m < 24; ++m) mx = fmaxf(mx, f[tid][m]);
        float e[24], sum = 0.f;
#pragma unroll
        for (int m = 0; m < 24; ++m) { e[m] = __expf(f[tid][m] - mx); sum += e[m]; }
        float inv = 1.0f / sum;
#pragma unroll
        for (int m = 0; m < 24; ++m) f[tid][m] = e[m] * inv;
    }
    __syncthreads();

    int o4 = tid * 4;
    // preload WG window columns for my 4 o's (coalesced float4, pipelined)
    float4 wgv[24];
#pragma unroll
    for (int m = 0; m < 24; ++m) {
        int jp = m / 3, kp = m - jp * 3;
        int tp = t - 7 + jp;
        float4 v = {0.f, 0.f, 0.f, 0.f};
        if (tp >= 0) v = *(const float4*)&Wg[(((b * 128 + tp) * 3 + kp) << 9) + o4];
        wgv[m] = v;
    }
    float4 wb4 = *(const float4*)&W_b[o4];

    float4 pooled = {-1e30f, -1e30f, -1e30f, -1e30f};
#pragma unroll
    for (int n = 0; n < 24; ++n) {
        float4 acc = {0.f, 0.f, 0.f, 0.f};
#pragma unroll
        for (int mq = 0; mq < 6; ++mq) {
            float4 p4 = *(const float4*)&f[n][mq * 4];
            float4 w0 = wgv[mq * 4 + 0], w1 = wgv[mq * 4 + 1];
            float4 w2 = wgv[mq * 4 + 2], w3 = wgv[mq * 4 + 3];
            acc.x += p4.x * w0.x + p4.y * w1.x + p4.z * w2.x + p4.w * w3.x;
            acc.y += p4.x * w0.y + p4.y * w1.y + p4.z * w2.y + p4.w * w3.y;
            acc.z += p4.x * w0.z + p4.y * w1.z + p4.z * w2.z + p4.w * w3.z;
            acc.w += p4.x * w0.w + p4.y * w1.w + p4.z * w2.w + p4.w * w3.w;
        }
        int j = n / 3, k = n - j * 3;
        int tp = t - 7 + j;
        float4 xv = {0.f, 0.f, 0.f, 0.f};
        if (tp >= 0) {
            const float* xin = (k == 0) ? out1 : ((k == 1) ? out2 : out3);
            int base = ((b << 9) + o4) * 128 + tp;
            xv.x = xin[base];
            xv.y = xin[base + 128];
            xv.z = xin[base + 256];
            xv.w = xin[base + 384];
        }
        float4 z = {acc.x + wb4.x + xv.x, acc.y + wb4.y + xv.y,
                    acc.z + wb4.z + xv.z, acc.w + wb4.w + xv.w};
        pooled.x = fmaxf(pooled.x, z.x);
        pooled.y = fmaxf(pooled.y, z.y);
        pooled.z = fmaxf(pooled.z, z.z);
        pooled.w = fmaxf(pooled.w, z.w);
    }
    *(float4*)&Pl[((t * 16 + b) << 9) + o4] = pooled;
}

// ---------------------------------------------------------------------------
// C[r][o] = lrelu( sum_c A[r][c] * W[o][c] )   A: MxK row-major, W: NxK row-major
// grid: (M/TS, N/TS), block 256
// ---------------------------------------------------------------------------
__global__ __launch_bounds__(256) void k_gemm_nt_act(const float* __restrict__ A,
                                                     const float* __restrict__ W,
                                                     float* __restrict__ C,
                                                     int M, int N, int K) {
    __shared__ float As[TS][KS + 1];
    __shared__ float Ws[TS][KS + 1];
    int tid = threadIdx.x;
    int tx = tid & 15, ty = tid >> 4;
    int i0 = blockIdx.x * TS;  // rows
    int j0 = blockIdx.y * TS;  // out cols
    float acc[4][4] = {};
    for (int k0 = 0; k0 < K; k0 += KS) {
        int c = tid & 15, r0 = tid >> 4;
#pragma unroll
        for (int l = 0; l < 4; ++l) {
            int r = r0 + l * 16;
            As[r][c] = A[(i0 + r) * K + k0 + c];
            Ws[r][c] = W[(j0 + r) * K + k0 + c];
        }
        __syncthreads();
#pragma unroll
        for (int kk = 0; kk < KS; ++kk) {
            float a[4], w[4];
#pragma unroll
            for (int i = 0; i < 4; ++i) a[i] = As[ty * 4 + i][kk];
#pragma unroll
            for (int j = 0; j < 4; ++j) w[j] = Ws[tx * 4 + j][kk];
#pragma unroll
            for (int i = 0; i < 4; ++i)
#pragma unroll
                for (int j = 0; j < 4; ++j) acc[i][j] += a[i] * w[j];
        }
        __syncthreads();
    }
#pragma unroll
    for (int i = 0; i < 4; ++i) {
        float4 v = {lrelu(acc[i][0]), lrelu(acc[i][1]), lrelu(acc[i][2]), lrelu(acc[i][3])};
        *(float4*)&C[(i0 + ty * 4 + i) * N + j0 + tx * 4] = v;
    }
}

// ---------------------------------------------------------------------------
// out[r] = lrelu( sum_c H[r][c]*p3w[c] + p3b )   one wave per row
// grid: M/4 blocks of 256
// ---------------------------------------------------------------------------
__global__ __launch_bounds__(256) void k_final(const float* __restrict__ H,
                                               const float* __restrict__ p3w,
                                               const float* __restrict__ p3b,
                                               float* __restrict__ out) {
    int r = blockIdx.x * 4 + (threadIdx.x >> 6);
    int lane = threadIdx.x & 63;
    const float4* h4 = (const float4*)&H[r << 9];
    const float4* w4 = (const float4*)p3w;
    float4 a1 = h4[lane], a2 = h4[lane + 64];
    float4 b1 = w4[lane], b2 = w4[lane + 64];
    float s = a1.x * b1.x + a1.y * b1.y + a1.z * b1.z + a1.w * b1.w +
              a2.x * b2.x + a2.y * b2.y + a2.z * b2.z + a2.w * b2.w;
#pragma unroll
    for (int off = 32; off; off >>= 1) s += __shfl_down(s, off, 64);
    if (lane == 0) out[r] = lrelu(s + p3b[0]);
}

extern "C" void kernel_launch(void* const* d_in, const int* in_sizes, int n_in,
                              void* d_out, int out_size, void* d_ws, size_t ws_size,
                              hipStream_t stream) {
    const float* out1 = (const float*)d_in[0];
    const float* out2 = (const float*)d_in[1];
    const float* out3 = (const float*)d_in[2];
    const float* theta_w = (const float*)d_in[3];
    const float* phi_w = (const float*)d_in[4];
    const float* g_w = (const float*)d_in[5];
    const float* W_w = (const float*)d_in[6];
    const float* W_b = (const float*)d_in[7];
    const float* p1_w = (const float*)d_in[8];
    const float* p2_w = (const float*)d_in[9];
    const float* p3_w = (const float*)d_in[10];
    const float* p3_b = (const float*)d_in[11];
    float* outp = (float*)d_out;

    // workspace layout (floats)
    float* ws = (float*)d_ws;
    float* Wg_w = ws;                    // 262144
    float* Th = Wg_w + 262144;           // 4718592
    float* Ph = Th + 4718592;            // 4718592
    float* Wg = Ph + 4718592;            // 4718592
    float* D = Wg + 4718592;             // 144*128*128 = 2359296
    float* Pl = D + 2359296;             // 2048*512 = 1048576
    float* h1 = Th;  // Th dead after k_gram
    float* h2 = Ph;  // Ph dead after k_gram

    // Wg_w = W_w @ g_w
    k_gemm_nn<<<dim3(8, 8), 256, 0, stream>>>(W_w, g_w, Wg_w, 512, 512, 512);
    // Theta / Phi / WG projections
    k_stageA<<<dim3(32, 8, 9), 256, 0, stream>>>(out1, out2, out3, theta_w, phi_w,
                                                 Wg_w, Th, Ph, Wg);
    // shared gram matrices
    k_gram<<<dim3(2, 2, 144), 256, 0, stream>>>(Th, Ph, D);
    // per-(b,t) softmax + mix + residual + pool
    k_mix<<<dim3(2048), 128, 0, stream>>>(out1, out2, out3, Wg, D, W_b, Pl);
    // MLP
    k_gemm_nt_act<<<dim3(32, 8), 256, 0, stream>>>(Pl, p1_w, h1, 2048, 512, 512);
    k_gemm_nt_act<<<dim3(32, 8), 256, 0, stream>>>(h1, p2_w, h2, 2048, 512, 512);
    k_final<<<dim3(512), 256, 0, stream>>>(h2, p3_w, p3_b, outp);
}

// Round 3
// 405.006 us; speedup vs baseline: 1.9195x; 1.9195x over previous
//
#include <hip/hip_runtime.h>

#define TS 64
#define KS 16

__device__ __forceinline__ float lrelu(float v) { return v >= 0.f ? v : 0.01f * v; }

// ---------------------------------------------------------------------------
// C[i][j] = sum_k A[i][k] * B[k][j]   (all row-major, M x K, K x N)
// grid: (N/TS, M/TS), block 256
// ---------------------------------------------------------------------------
__global__ __launch_bounds__(256) void k_gemm_nn(const float* __restrict__ A,
                                                 const float* __restrict__ B,
                                                 float* __restrict__ C,
                                                 int M, int N, int K) {
    __shared__ float As[TS][KS + 1];  // As[i][k] padded
    __shared__ float Bs[KS][TS];      // Bs[k][j]
    int tid = threadIdx.x;
    int tx = tid & 15, ty = tid >> 4;
    int i0 = blockIdx.y * TS, j0 = blockIdx.x * TS;
    float acc[4][4] = {};
    for (int k0 = 0; k0 < K; k0 += KS) {
        {
            int c = tid & 15, r0 = tid >> 4;
#pragma unroll
            for (int l = 0; l < 4; ++l) {
                int r = r0 + l * 16;
                As[r][c] = A[(i0 + r) * K + k0 + c];
            }
        }
        {
            int j = tid & 63, r0 = tid >> 6;
#pragma unroll
            for (int l = 0; l < 4; ++l) {
                int r = r0 + l * 4;
                Bs[r][j] = B[(k0 + r) * N + j0 + j];
            }
        }
        __syncthreads();
#pragma unroll
        for (int kk = 0; kk < KS; ++kk) {
            float4 b4 = *(const float4*)&Bs[kk][tx * 4];
#pragma unroll
            for (int i = 0; i < 4; ++i) {
                float a = As[ty * 4 + i][kk];
                acc[i][0] += a * b4.x; acc[i][1] += a * b4.y;
                acc[i][2] += a * b4.z; acc[i][3] += a * b4.w;
            }
        }
        __syncthreads();
    }
#pragma unroll
    for (int i = 0; i < 4; ++i) {
        float4 v = {acc[i][0], acc[i][1], acc[i][2], acc[i][3]};
        *(float4*)&C[(i0 + ty * 4 + i) * N + j0 + tx * 4] = v;
    }
}

// ---------------------------------------------------------------------------
// Stage A: Out[b][t][k][o] = sum_c Wmat[o][c] * In_k[b][c][t]
// grid: (B*T/TS, C/TS, 9)  z = wsel*3 + kin ; block 256
// ---------------------------------------------------------------------------
__global__ __launch_bounds__(256) void k_stageA(
    const float* __restrict__ out1, const float* __restrict__ out2,
    const float* __restrict__ out3, const float* __restrict__ theta_w,
    const float* __restrict__ phi_w, const float* __restrict__ wg_w,
    float* __restrict__ Th, float* __restrict__ Ph, float* __restrict__ Wg) {
    const int Cc = 512, T = 128;
    int wsel = blockIdx.z / 3, kin = blockIdx.z % 3;
    const float* W = (wsel == 0) ? theta_w : ((wsel == 1) ? phi_w : wg_w);
    const float* In = (kin == 0) ? out1 : ((kin == 1) ? out2 : out3);
    float* Out = (wsel == 0) ? Th : ((wsel == 1) ? Ph : Wg);

    int col0 = blockIdx.x * TS;
    int b = col0 >> 7, t0 = col0 & 127;
    int o0 = blockIdx.y * TS;

    __shared__ float As[TS][KS + 1];  // As[o][k]
    __shared__ float Bs[KS][TS];      // Bs[k][t]
    int tid = threadIdx.x;
    int tx = tid & 15, ty = tid >> 4;
    float acc[4][4] = {};  // [i=o][j=t]

    for (int k0 = 0; k0 < 512; k0 += KS) {
        {
            int c = tid & 15, r0 = tid >> 4;
#pragma unroll
            for (int l = 0; l < 4; ++l) {
                int r = r0 + l * 16;
                As[r][c] = W[(o0 + r) * Cc + k0 + c];
            }
        }
        {
            int j = tid & 63, r0 = tid >> 6;
#pragma unroll
            for (int l = 0; l < 4; ++l) {
                int r = r0 + l * 4;
                Bs[r][j] = In[(b * Cc + k0 + r) * T + t0 + j];
            }
        }
        __syncthreads();
#pragma unroll
        for (int kk = 0; kk < KS; ++kk) {
            float4 b4 = *(const float4*)&Bs[kk][tx * 4];
#pragma unroll
            for (int i = 0; i < 4; ++i) {
                float a = As[ty * 4 + i][kk];
                acc[i][0] += a * b4.x; acc[i][1] += a * b4.y;
                acc[i][2] += a * b4.z; acc[i][3] += a * b4.w;
            }
        }
        __syncthreads();
    }
#pragma unroll
    for (int jj = 0; jj < 4; ++jj) {
        int t = t0 + tx * 4 + jj;
        float4 v = {acc[0][jj], acc[1][jj], acc[2][jj], acc[3][jj]};
        *(float4*)&Out[(((b * T + t) * 3 + kin) << 9) + o0 + ty * 4] = v;
    }
}

// ---------------------------------------------------------------------------
// Band-gram as full 128x128 gram per (b, k, k'):
// D[mat][t1][t2] = sum_o Th[b][t1][k][o] * Ph[b][t2][k'][o], mat = (b*3+k)*3+k'
// grid: (2, 2, 144), block 256 (64x64 output tile per block)
// ---------------------------------------------------------------------------
__global__ __launch_bounds__(256) void k_gram(const float* __restrict__ Th,
                                              const float* __restrict__ Ph,
                                              float* __restrict__ D) {
    int mat = blockIdx.z;
    int b = mat / 9, kk9 = mat % 9, k = kk9 / 3, kp = kk9 % 3;
    const float* A0 = Th + (b * 128 * 3 + k) * 512;   // row t1: + t1*1536
    const float* B0 = Ph + (b * 128 * 3 + kp) * 512;  // row t2: + t2*1536

    int i0 = blockIdx.y * TS, j0 = blockIdx.x * TS;
    __shared__ float As[TS][KS + 1];
    __shared__ float Bs[TS][KS + 1];
    int tid = threadIdx.x;
    int tx = tid & 15, ty = tid >> 4;
    float acc[4][4] = {};
    for (int k0 = 0; k0 < 512; k0 += KS) {
        int c = tid & 15, r0 = tid >> 4;
#pragma unroll
        for (int l = 0; l < 4; ++l) {
            int r = r0 + l * 16;
            As[r][c] = A0[(i0 + r) * 1536 + k0 + c];
            Bs[r][c] = B0[(j0 + r) * 1536 + k0 + c];
        }
        __syncthreads();
#pragma unroll
        for (int kk = 0; kk < KS; ++kk) {
            float a[4], bv[4];
#pragma unroll
            for (int i = 0; i < 4; ++i) a[i] = As[ty * 4 + i][kk];
#pragma unroll
            for (int j = 0; j < 4; ++j) bv[j] = Bs[tx * 4 + j][kk];
#pragma unroll
            for (int i = 0; i < 4; ++i)
#pragma unroll
                for (int j = 0; j < 4; ++j) acc[i][j] += a[i] * bv[j];
        }
        __syncthreads();
    }
#pragma unroll
    for (int i = 0; i < 4; ++i) {
        float4 v = {acc[i][0], acc[i][1], acc[i][2], acc[i][3]};
        *(float4*)&D[(mat * 128 + i0 + ty * 4 + i) * 128 + j0 + tx * 4] = v;
    }
}

// ---------------------------------------------------------------------------
// Transpose inputs to Xt[(b*T+t)*3+k][o] = in_k[b][o][t]  (o fastest, matches Wg)
// grid: (16, 4, 48) z=b*3+k ; block (32, 8)
// ---------------------------------------------------------------------------
__global__ __launch_bounds__(256) void k_xpose(const float* __restrict__ out1,
                                               const float* __restrict__ out2,
                                               const float* __restrict__ out3,
                                               float* __restrict__ Xt) {
    int z = blockIdx.z;
    int b = z / 3, k = z - b * 3;
    const float* In = (k == 0) ? out1 : ((k == 1) ? out2 : out3);
    int o0 = blockIdx.x * 32, t0 = blockIdx.y * 32;
    __shared__ float tile[32][33];
    int tx = threadIdx.x, ty = threadIdx.y;
#pragma unroll
    for (int i = 0; i < 4; ++i) {
        int o = o0 + ty + i * 8;
        tile[ty + i * 8][tx] = In[(b * 512 + o) * 128 + t0 + tx];
    }
    __syncthreads();
#pragma unroll
    for (int i = 0; i < 4; ++i) {
        int t = t0 + ty + i * 8;
        Xt[(((b * 128 + t) * 3 + k) << 9) + o0 + tx] = tile[tx][ty + i * 8];
    }
}

// ---------------------------------------------------------------------------
// Mix: per (b,t): gather f (24x24) from D, softmax rows, then
// pooled[o] = max_n ( sum_m P[n][m]*WG_win[o][m] + W_b[o] + Xt_win[o][n] )
// grid: 2048 (b*128+t), block 512 (one o per thread)
// ---------------------------------------------------------------------------
__global__ __launch_bounds__(512) void k_mix(
    const float* __restrict__ Xt, const float* __restrict__ Wg,
    const float* __restrict__ D, const float* __restrict__ W_b,
    float* __restrict__ Pl) {
    int bid = blockIdx.x;
    int b = bid >> 7, t = bid & 127;
    int tid = threadIdx.x;

    __shared__ float Pm[24][28];

    // gather f from D (zeros where window hangs off the front)
    for (int idx = tid; idx < 576; idx += 512) {
        int n = idx / 24, m = idx - n * 24;
        int j = n / 3, k = n - j * 3;
        int jp = m / 3, kp = m - jp * 3;
        int t1 = t - 7 + j, t2 = t - 7 + jp;
        float v = 0.f;
        if (t1 >= 0 && t2 >= 0)
            v = D[((((b * 3 + k) * 3 + kp) * 128 + t1) << 7) + t2];
        Pm[n][m] = v;
    }
    __syncthreads();

    // softmax rows
    if (tid < 24) {
        float mx = -1e30f;
#pragma unroll
        for (int m = 0; m < 24; ++m) mx = fmaxf(mx, Pm[tid][m]);
        float e[24], sum = 0.f;
#pragma unroll
        for (int m = 0; m < 24; ++m) { e[m] = __expf(Pm[tid][m] - mx); sum += e[m]; }
        float inv = 1.0f / sum;
#pragma unroll
        for (int m = 0; m < 24; ++m) Pm[tid][m] = e[m] * inv;
    }
    __syncthreads();

    // phase 2: one o per thread, all loads coalesced along o
    int o = tid;
    float wg[24], xw[24];
#pragma unroll
    for (int m = 0; m < 24; ++m) {
        int j = m / 3, k = m - j * 3;
        int tp = t - 7 + j;
        int base = (((b * 128 + tp) * 3 + k) << 9) + o;
        wg[m] = (tp >= 0) ? Wg[base] : 0.f;
        xw[m] = (tp >= 0) ? Xt[base] : 0.f;
    }
    float wb = W_b[o];
    float pooled = -1e30f;
#pragma unroll
    for (int n = 0; n < 24; ++n) {
        float s = 0.f;
#pragma unroll
        for (int m = 0; m < 24; ++m) s += Pm[n][m] * wg[m];
        s += wb + xw[n];
        pooled = fmaxf(pooled, s);
    }
    Pl[((t * 16 + b) << 9) + o] = pooled;
}

// ---------------------------------------------------------------------------
// C[r][o] = lrelu( sum_c A[r][c] * W[o][c] )   A: MxK row-major, W: NxK row-major
// grid: (M/TS, N/TS), block 256
// ---------------------------------------------------------------------------
__global__ __launch_bounds__(256) void k_gemm_nt_act(const float* __restrict__ A,
                                                     const float* __restrict__ W,
                                                     float* __restrict__ C,
                                                     int M, int N, int K) {
    __shared__ float As[TS][KS + 1];
    __shared__ float Ws[TS][KS + 1];
    int tid = threadIdx.x;
    int tx = tid & 15, ty = tid >> 4;
    int i0 = blockIdx.x * TS;  // rows
    int j0 = blockIdx.y * TS;  // out cols
    float acc[4][4] = {};
    for (int k0 = 0; k0 < K; k0 += KS) {
        int c = tid & 15, r0 = tid >> 4;
#pragma unroll
        for (int l = 0; l < 4; ++l) {
            int r = r0 + l * 16;
            As[r][c] = A[(i0 + r) * K + k0 + c];
            Ws[r][c] = W[(j0 + r) * K + k0 + c];
        }
        __syncthreads();
#pragma unroll
        for (int kk = 0; kk < KS; ++kk) {
            float a[4], w[4];
#pragma unroll
            for (int i = 0; i < 4; ++i) a[i] = As[ty * 4 + i][kk];
#pragma unroll
            for (int j = 0; j < 4; ++j) w[j] = Ws[tx * 4 + j][kk];
#pragma unroll
            for (int i = 0; i < 4; ++i)
#pragma unroll
                for (int j = 0; j < 4; ++j) acc[i][j] += a[i] * w[j];
        }
        __syncthreads();
    }
#pragma unroll
    for (int i = 0; i < 4; ++i) {
        float4 v = {lrelu(acc[i][0]), lrelu(acc[i][1]), lrelu(acc[i][2]), lrelu(acc[i][3])};
        *(float4*)&C[(i0 + ty * 4 + i) * N + j0 + tx * 4] = v;
    }
}

// ---------------------------------------------------------------------------
// out[r] = lrelu( sum_c H[r][c]*p3w[c] + p3b )   one wave per row
// grid: M/4 blocks of 256
// ---------------------------------------------------------------------------
__global__ __launch_bounds__(256) void k_final(const float* __restrict__ H,
                                               const float* __restrict__ p3w,
                                               const float* __restrict__ p3b,
                                               float* __restrict__ out) {
    int r = blockIdx.x * 4 + (threadIdx.x >> 6);
    int lane = threadIdx.x & 63;
    const float4* h4 = (const float4*)&H[r << 9];
    const float4* w4 = (const float4*)p3w;
    float4 a1 = h4[lane], a2 = h4[lane + 64];
    float4 b1 = w4[lane], b2 = w4[lane + 64];
    float s = a1.x * b1.x + a1.y * b1.y + a1.z * b1.z + a1.w * b1.w +
              a2.x * b2.x + a2.y * b2.y + a2.z * b2.z + a2.w * b2.w;
#pragma unroll
    for (int off = 32; off; off >>= 1) s += __shfl_down(s, off, 64);
    if (lane == 0) out[r] = lrelu(s + p3b[0]);
}

extern "C" void kernel_launch(void* const* d_in, const int* in_sizes, int n_in,
                              void* d_out, int out_size, void* d_ws, size_t ws_size,
                              hipStream_t stream) {
    const float* out1 = (const float*)d_in[0];
    const float* out2 = (const float*)d_in[1];
    const float* out3 = (const float*)d_in[2];
    const float* theta_w = (const float*)d_in[3];
    const float* phi_w = (const float*)d_in[4];
    const float* g_w = (const float*)d_in[5];
    const float* W_w = (const float*)d_in[6];
    const float* W_b = (const float*)d_in[7];
    const float* p1_w = (const float*)d_in[8];
    const float* p2_w = (const float*)d_in[9];
    const float* p3_w = (const float*)d_in[10];
    const float* p3_b = (const float*)d_in[11];
    float* outp = (float*)d_out;

    // workspace layout (floats)
    float* ws = (float*)d_ws;
    float* Wg_w = ws;                    // 262144
    float* Th = Wg_w + 262144;           // 4718592 (dead after k_gram)
    float* Ph = Th + 4718592;            // 4718592 (dead after k_gram)
    float* Wg = Ph + 4718592;            // 4718592 (dead after k_mix)
    float* D = Wg + 4718592;             // 144*128*128 = 2359296
    float* Pl = D + 2359296;             // 2048*512 = 1048576
    float* Xt = Th;  // alias: written by k_xpose AFTER k_gram
    float* h1 = Ph;  // alias: written after k_mix
    float* h2 = Wg;  // alias: written after gemm1 (Wg dead after k_mix)

    // Wg_w = W_w @ g_w
    k_gemm_nn<<<dim3(8, 8), 256, 0, stream>>>(W_w, g_w, Wg_w, 512, 512, 512);
    // Theta / Phi / WG projections
    k_stageA<<<dim3(32, 8, 9), 256, 0, stream>>>(out1, out2, out3, theta_w, phi_w,
                                                 Wg_w, Th, Ph, Wg);
    // shared gram matrices
    k_gram<<<dim3(2, 2, 144), 256, 0, stream>>>(Th, Ph, D);
    // transpose inputs to o-fastest layout (overwrites Th — dead)
    k_xpose<<<dim3(16, 4, 48), dim3(32, 8), 0, stream>>>(out1, out2, out3, Xt);
    // per-(b,t) softmax + mix + residual + pool
    k_mix<<<dim3(2048), 512, 0, stream>>>(Xt, Wg, D, W_b, Pl);
    // MLP
    k_gemm_nt_act<<<dim3(32, 8), 256, 0, stream>>>(Pl, p1_w, h1, 2048, 512, 512);
    k_gemm_nt_act<<<dim3(32, 8), 256, 0, stream>>>(h1, p2_w, h2, 2048, 512, 512);
    k_final<<<dim3(512), 256, 0, stream>>>(h2, p3_w, p3_b, outp);
}

// Round 4
// 206.391 us; speedup vs baseline: 3.7668x; 1.9623x over previous
//
#include <hip/hip_runtime.h>

typedef __attribute__((ext_vector_type(8))) short short8;
typedef __attribute__((ext_vector_type(4))) float float4v;
typedef __attribute__((ext_vector_type(4))) unsigned int uint4v;
typedef __attribute__((ext_vector_type(4))) unsigned short ushort4v;

__device__ __forceinline__ float lrelu(float v) { return v >= 0.f ? v : 0.01f * v; }

__device__ __forceinline__ unsigned short f2bf(float x) {
    union { float f; unsigned u; } c; c.f = x;
    unsigned r = (c.u + 0x7FFFu + ((c.u >> 16) & 1u)) >> 16;
    return (unsigned short)r;
}
__device__ __forceinline__ float bf2f(unsigned short h) {
    union { unsigned u; float f; } c; c.u = ((unsigned)h) << 16;
    return c.f;
}

// ===========================================================================
// Shared MFMA core: C[128x128] += A[128xK] * B[128xK]^T, K=512, split-bf16.
// A,B given as bf16 hi/lo pairs, rows K-contiguous with leading dims lda/ldb.
// acc: fp32, effective fp32 precision via hi*hi + hi*lo + lo*hi.
// Block = 256 threads (4 waves, 2x2 of 64x64 per wave).
// LDS = 4 tiles [128][64] bf16, XOR-swizzled (chunk ^= row&7) -> conflict-free.
// ===========================================================================
__device__ __forceinline__ void mfma_core(
    const unsigned short* __restrict__ Ah, const unsigned short* __restrict__ Al, int lda,
    const unsigned short* __restrict__ Bh, const unsigned short* __restrict__ Bl, int ldb,
    unsigned short* lds, float4v acc[4][4]) {
    const int tid = threadIdx.x;
    const int lane = tid & 63, wave = tid >> 6;
    const int wm = wave >> 1, wn = wave & 1;
    const int l15 = lane & 15, lhi = lane >> 4;
    unsigned short* LAh = lds;
    unsigned short* LAl = lds + 8192;
    unsigned short* LBh = lds + 16384;
    unsigned short* LBl = lds + 24576;

    for (int k0 = 0; k0 < 512; k0 += 64) {
#pragma unroll
        for (int tile = 0; tile < 4; ++tile) {
            const unsigned short* s = (tile == 0) ? Ah : (tile == 1) ? Al : (tile == 2) ? Bh : Bl;
            int ld = (tile < 2) ? lda : ldb;
            unsigned short* d = (tile == 0) ? LAh : (tile == 1) ? LAl : (tile == 2) ? LBh : LBl;
#pragma unroll
            for (int it = 0; it < 4; ++it) {
                int idx = it * 256 + tid;
                int row = idx >> 3, ch = idx & 7;
                uint4v v = *(const uint4v*)&s[row * ld + k0 + ch * 8];
                *(uint4v*)&d[row * 64 + ((ch ^ (row & 7)) * 8)] = v;
            }
        }
        __syncthreads();
#pragma unroll
        for (int ks = 0; ks < 2; ++ks) {
            short8 ah[4], al[4], bh[4], bl[4];
#pragma unroll
            for (int m = 0; m < 4; ++m) {
                int r = wm * 64 + m * 16 + l15;
                int off = r * 64 + (((ks * 4 + lhi) ^ (r & 7)) * 8);
                ah[m] = *(const short8*)&LAh[off];
                al[m] = *(const short8*)&LAl[off];
            }
#pragma unroll
            for (int n = 0; n < 4; ++n) {
                int r = wn * 64 + n * 16 + l15;
                int off = r * 64 + (((ks * 4 + lhi) ^ (r & 7)) * 8);
                bh[n] = *(const short8*)&LBh[off];
                bl[n] = *(const short8*)&LBl[off];
            }
#pragma unroll
            for (int m = 0; m < 4; ++m)
#pragma unroll
                for (int n = 0; n < 4; ++n) {
                    acc[m][n] = __builtin_amdgcn_mfma_f32_16x16x32_bf16(ah[m], bh[n], acc[m][n], 0, 0, 0);
                    acc[m][n] = __builtin_amdgcn_mfma_f32_16x16x32_bf16(ah[m], bl[n], acc[m][n], 0, 0, 0);
                    acc[m][n] = __builtin_amdgcn_mfma_f32_16x16x32_bf16(al[m], bh[n], acc[m][n], 0, 0, 0);
                }
        }
        __syncthreads();
    }
}

// ---------------------------------------------------------------------------
// Wg_w = W_w @ g_w  (fp32, small: 0.27 GFLOP)
// ---------------------------------------------------------------------------
#define TS 64
#define KS 16
__global__ __launch_bounds__(256) void k_gemm_nn(const float* __restrict__ A,
                                                 const float* __restrict__ B,
                                                 float* __restrict__ C,
                                                 int M, int N, int K) {
    __shared__ float As[TS][KS + 1];
    __shared__ float Bs[KS][TS];
    int tid = threadIdx.x;
    int tx = tid & 15, ty = tid >> 4;
    int i0 = blockIdx.y * TS, j0 = blockIdx.x * TS;
    float acc[4][4] = {};
    for (int k0 = 0; k0 < K; k0 += KS) {
        {
            int c = tid & 15, r0 = tid >> 4;
#pragma unroll
            for (int l = 0; l < 4; ++l) As[r0 + l * 16][c] = A[(i0 + r0 + l * 16) * K + k0 + c];
        }
        {
            int j = tid & 63, r0 = tid >> 6;
#pragma unroll
            for (int l = 0; l < 4; ++l) Bs[r0 + l * 4][j] = B[(k0 + r0 + l * 4) * N + j0 + j];
        }
        __syncthreads();
#pragma unroll
        for (int kk = 0; kk < KS; ++kk) {
            float4 b4 = *(const float4*)&Bs[kk][tx * 4];
#pragma unroll
            for (int i = 0; i < 4; ++i) {
                float a = As[ty * 4 + i][kk];
                acc[i][0] += a * b4.x; acc[i][1] += a * b4.y;
                acc[i][2] += a * b4.z; acc[i][3] += a * b4.w;
            }
        }
        __syncthreads();
    }
#pragma unroll
    for (int i = 0; i < 4; ++i) {
        float4 v = {acc[i][0], acc[i][1], acc[i][2], acc[i][3]};
        *(float4*)&C[(i0 + ty * 4 + i) * N + j0 + tx * 4] = v;
    }
}

// ---------------------------------------------------------------------------
// Split fp32 weight matrices into bf16 hi/lo. grid (256, 5), block 256.
// z: 0=theta->Ws rows 0-511, 1=phi->rows 512-1023, 2=Wg_w->rows 1024-1535,
//    3=p1_w, 4=p2_w
// ---------------------------------------------------------------------------
__global__ __launch_bounds__(256) void k_split_w(
    const float* __restrict__ tw, const float* __restrict__ fw,
    const float* __restrict__ wgw, const float* __restrict__ p1w,
    const float* __restrict__ p2w, unsigned short* __restrict__ Whi,
    unsigned short* __restrict__ Wlo, unsigned short* __restrict__ p1h,
    unsigned short* __restrict__ p1l, unsigned short* __restrict__ p2h,
    unsigned short* __restrict__ p2l) {
    int z = blockIdx.y;
    const float* src = (z == 0) ? tw : (z == 1) ? fw : (z == 2) ? wgw : (z == 3) ? p1w : p2w;
    unsigned short* dh = (z < 3) ? Whi + z * 262144 : ((z == 3) ? p1h : p2h);
    unsigned short* dl = (z < 3) ? Wlo + z * 262144 : ((z == 3) ? p1l : p2l);
    int i4 = blockIdx.x * 256 + threadIdx.x;
    float4v v = ((const float4v*)src)[i4];
    ushort4v h, l;
#pragma unroll
    for (int j = 0; j < 4; ++j) {
        h[j] = f2bf(v[j]);
        l[j] = f2bf(v[j] - bf2f(h[j]));
    }
    ((ushort4v*)dh)[i4] = h;
    ((ushort4v*)dl)[i4] = l;
}

// ---------------------------------------------------------------------------
// Transpose+split inputs: Xt[((b*128+t)*3+k)*512 + c] = in_k[b][c][t] (hi/lo)
// grid (16, 4, 48), block (32,8)
// ---------------------------------------------------------------------------
__global__ __launch_bounds__(256) void k_splitx(const float* __restrict__ o1,
                                                const float* __restrict__ o2,
                                                const float* __restrict__ o3,
                                                unsigned short* __restrict__ Xh,
                                                unsigned short* __restrict__ Xl) {
    int z = blockIdx.z;
    int b = z / 3, k = z - b * 3;
    const float* In = (k == 0) ? o1 : ((k == 1) ? o2 : o3);
    int c0 = blockIdx.x * 32, t0 = blockIdx.y * 32;
    __shared__ float tile[32][33];
    int tx = threadIdx.x, ty = threadIdx.y;
#pragma unroll
    for (int i = 0; i < 4; ++i)
        tile[ty + i * 8][tx] = In[(b * 512 + c0 + ty + i * 8) * 128 + t0 + tx];
    __syncthreads();
#pragma unroll
    for (int i = 0; i < 4; ++i) {
        int t = t0 + ty + i * 8;
        float v = tile[tx][ty + i * 8];
        unsigned short h = f2bf(v), l = f2bf(v - bf2f(h));
        int idx = ((b * 128 + t) * 3 + k) * 512 + c0 + tx;
        Xh[idx] = h;
        Xl[idx] = l;
    }
}

// ---------------------------------------------------------------------------
// Stage A via MFMA: C[o,(b,kin,t)] = Wstack[o,:] . Xt[(b,kin,t),:]
// grid (48, 12): x = b*3+kin, y = o-tile. Epilogue: wsel=y>>2
//   wsel 0 -> Th hi/lo (bf16), 1 -> Ph hi/lo, 2 -> Wg fp32
// ---------------------------------------------------------------------------
__global__ __launch_bounds__(256) void k_ga(
    const unsigned short* __restrict__ Whi, const unsigned short* __restrict__ Wlo,
    const unsigned short* __restrict__ Xh, const unsigned short* __restrict__ Xl,
    unsigned short* __restrict__ Thh, unsigned short* __restrict__ Thl,
    unsigned short* __restrict__ Phh, unsigned short* __restrict__ Phl,
    float* __restrict__ Wg) {
    __shared__ unsigned short lds[32768];
    int bk = blockIdx.x, y = blockIdx.y;
    int b = bk / 3, kin = bk - b * 3;
    int bbase = (b * 384 + kin) * 512;
    float4v acc[4][4];
#pragma unroll
    for (int m = 0; m < 4; ++m)
#pragma unroll
        for (int n = 0; n < 4; ++n) acc[m][n] = (float4v){0.f, 0.f, 0.f, 0.f};

    mfma_core(Whi + y * 128 * 512, Wlo + y * 128 * 512, 512,
              Xh + bbase, Xl + bbase, 1536, lds, acc);

    int lane = threadIdx.x & 63, wave = threadIdx.x >> 6;
    int wm = wave >> 1, wn = wave & 1, l15 = lane & 15, lhi = lane >> 4;
    int wsel = y >> 2, o0 = (y & 3) * 128;
#pragma unroll
    for (int m = 0; m < 4; ++m)
#pragma unroll
        for (int n = 0; n < 4; ++n) {
            int o_in = wm * 64 + m * 16 + lhi * 4;
            int t = wn * 64 + n * 16 + l15;
            int idx = bbase + t * 1536 + o0 + o_in;
            if (wsel == 2) {
                *(float4v*)&Wg[idx] = acc[m][n];
            } else {
                ushort4v h, l;
#pragma unroll
                for (int i = 0; i < 4; ++i) {
                    float v = acc[m][n][i];
                    h[i] = f2bf(v);
                    l[i] = f2bf(v - bf2f(h[i]));
                }
                unsigned short* dh = wsel ? Phh : Thh;
                unsigned short* dl = wsel ? Phl : Thl;
                *(ushort4v*)&dh[idx] = h;
                *(ushort4v*)&dl[idx] = l;
            }
        }
}

// ---------------------------------------------------------------------------
// Gram via MFMA: D[mat][t1][t2] = Th[b,t1,k,:] . Ph[b,t2,kp,:]
// grid 144: mat = (b*3+k)*3+kp
// ---------------------------------------------------------------------------
__global__ __launch_bounds__(256) void k_gram2(
    const unsigned short* __restrict__ Thh, const unsigned short* __restrict__ Thl,
    const unsigned short* __restrict__ Phh, const unsigned short* __restrict__ Phl,
    float* __restrict__ D) {
    __shared__ unsigned short lds[32768];
    int mat = blockIdx.x;
    int b = mat / 9, r9 = mat - b * 9, k = r9 / 3, kp = r9 - k * 3;
    int Ab = (b * 384 + k) * 512, Bb = (b * 384 + kp) * 512;
    float4v acc[4][4];
#pragma unroll
    for (int m = 0; m < 4; ++m)
#pragma unroll
        for (int n = 0; n < 4; ++n) acc[m][n] = (float4v){0.f, 0.f, 0.f, 0.f};

    mfma_core(Thh + Ab, Thl + Ab, 1536, Phh + Bb, Phl + Bb, 1536, lds, acc);

    int lane = threadIdx.x & 63, wave = threadIdx.x >> 6;
    int wm = wave >> 1, wn = wave & 1, l15 = lane & 15, lhi = lane >> 4;
    float* Dm = D + mat * 16384;
#pragma unroll
    for (int m = 0; m < 4; ++m)
#pragma unroll
        for (int n = 0; n < 4; ++n) {
            int t2 = wn * 64 + n * 16 + l15;
#pragma unroll
            for (int i = 0; i < 4; ++i) {
                int t1 = wm * 64 + m * 16 + lhi * 4 + i;
                Dm[t1 * 128 + t2] = acc[m][n][i];
            }
        }
}

// ---------------------------------------------------------------------------
// MLP layer via MFMA: C[r][o] = lrelu( A[r,:] . W[o,:] )
// grid (16, 4): r-tile, o-tile. SPLIT_OUT: write bf16 hi/lo, else fp32.
// ---------------------------------------------------------------------------
template <bool SPLIT_OUT>
__global__ __launch_bounds__(256) void k_mlp(
    const unsigned short* __restrict__ Ahi, const unsigned short* __restrict__ Alo,
    const unsigned short* __restrict__ Bhi, const unsigned short* __restrict__ Blo,
    unsigned short* __restrict__ Ch, unsigned short* __restrict__ Cl,
    float* __restrict__ Cf) {
    __shared__ unsigned short lds[32768];
    int r0 = blockIdx.x * 128, o0 = blockIdx.y * 128;
    float4v acc[4][4];
#pragma unroll
    for (int m = 0; m < 4; ++m)
#pragma unroll
        for (int n = 0; n < 4; ++n) acc[m][n] = (float4v){0.f, 0.f, 0.f, 0.f};

    mfma_core(Ahi + r0 * 512, Alo + r0 * 512, 512, Bhi + o0 * 512, Blo + o0 * 512, 512, lds, acc);

    int lane = threadIdx.x & 63, wave = threadIdx.x >> 6;
    int wm = wave >> 1, wn = wave & 1, l15 = lane & 15, lhi = lane >> 4;
#pragma unroll
    for (int m = 0; m < 4; ++m)
#pragma unroll
        for (int n = 0; n < 4; ++n) {
            int o = o0 + wn * 64 + n * 16 + l15;
#pragma unroll
            for (int i = 0; i < 4; ++i) {
                int r = r0 + wm * 64 + m * 16 + lhi * 4 + i;
                float v = lrelu(acc[m][n][i]);
                if (SPLIT_OUT) {
                    unsigned short h = f2bf(v), l = f2bf(v - bf2f(h));
                    Ch[r * 512 + o] = h;
                    Cl[r * 512 + o] = l;
                } else {
                    Cf[r * 512 + o] = v;
                }
            }
        }
}

// ---------------------------------------------------------------------------
// Mix: per (b,t): gather f (24x24) from D, softmax rows, then
// pooled[o] = max_n ( sum_m P[n][m]*WG_win[o][m] + W_b[o] + X_win[o][n] )
// grid 2048, block 512. Pl written as bf16 hi/lo.
// ---------------------------------------------------------------------------
__global__ __launch_bounds__(512) void k_mix(
    const unsigned short* __restrict__ Xh, const unsigned short* __restrict__ Xl,
    const float* __restrict__ Wg, const float* __restrict__ D,
    const float* __restrict__ W_b, unsigned short* __restrict__ Plh,
    unsigned short* __restrict__ Pll) {
    int bid = blockIdx.x;
    int b = bid >> 7, t = bid & 127;
    int tid = threadIdx.x;

    __shared__ float Pm[24][28];

    for (int idx = tid; idx < 576; idx += 512) {
        int n = idx / 24, m = idx - n * 24;
        int j = n / 3, k = n - j * 3;
        int jp = m / 3, kp = m - jp * 3;
        int t1 = t - 7 + j, t2 = t - 7 + jp;
        float v = 0.f;
        if (t1 >= 0 && t2 >= 0)
            v = D[((((b * 3 + k) * 3 + kp) * 128 + t1) << 7) + t2];
        Pm[n][m] = v;
    }
    __syncthreads();

    if (tid < 24) {
        float mx = -1e30f;
#pragma unroll
        for (int m = 0; m < 24; ++m) mx = fmaxf(mx, Pm[tid][m]);
        float e[24], sum = 0.f;
#pragma unroll
        for (int m = 0; m < 24; ++m) { e[m] = __expf(Pm[tid][m] - mx); sum += e[m]; }
        float inv = 1.0f / sum;
#pragma unroll
        for (int m = 0; m < 24; ++m) Pm[tid][m] = e[m] * inv;
    }
    __syncthreads();

    int o = tid;
    float wg[24], xw[24];
#pragma unroll
    for (int m = 0; m < 24; ++m) {
        int j = m / 3, k = m - j * 3;
        int tp = t - 7 + j;
        int base = (((b * 128 + tp) * 3 + k) << 9) + o;
        wg[m] = (tp >= 0) ? Wg[base] : 0.f;
        xw[m] = (tp >= 0) ? (bf2f(Xh[base]) + bf2f(Xl[base])) : 0.f;
    }
    float wb = W_b[o];
    float pooled = -1e30f;
#pragma unroll
    for (int n = 0; n < 24; ++n) {
        float s = 0.f;
#pragma unroll
        for (int m = 0; m < 24; ++m) s += Pm[n][m] * wg[m];
        s += wb + xw[n];
        pooled = fmaxf(pooled, s);
    }
    int oidx = ((t * 16 + b) << 9) + o;
    unsigned short h = f2bf(pooled), l = f2bf(pooled - bf2f(h));
    Plh[oidx] = h;
    Pll[oidx] = l;
}

// ---------------------------------------------------------------------------
// out[r] = lrelu( sum_c H[r][c]*p3w[c] + p3b )   one wave per row
// ---------------------------------------------------------------------------
__global__ __launch_bounds__(256) void k_final(const float* __restrict__ H,
                                               const float* __restrict__ p3w,
                                               const float* __restrict__ p3b,
                                               float* __restrict__ out) {
    int r = blockIdx.x * 4 + (threadIdx.x >> 6);
    int lane = threadIdx.x & 63;
    const float4* h4 = (const float4*)&H[r << 9];
    const float4* w4 = (const float4*)p3w;
    float4 a1 = h4[lane], a2 = h4[lane + 64];
    float4 b1 = w4[lane], b2 = w4[lane + 64];
    float s = a1.x * b1.x + a1.y * b1.y + a1.z * b1.z + a1.w * b1.w +
              a2.x * b2.x + a2.y * b2.y + a2.z * b2.z + a2.w * b2.w;
#pragma unroll
    for (int off = 32; off; off >>= 1) s += __shfl_down(s, off, 64);
    if (lane == 0) out[r] = lrelu(s + p3b[0]);
}

extern "C" void kernel_launch(void* const* d_in, const int* in_sizes, int n_in,
                              void* d_out, int out_size, void* d_ws, size_t ws_size,
                              hipStream_t stream) {
    const float* out1 = (const float*)d_in[0];
    const float* out2 = (const float*)d_in[1];
    const float* out3 = (const float*)d_in[2];
    const float* theta_w = (const float*)d_in[3];
    const float* phi_w = (const float*)d_in[4];
    const float* g_w = (const float*)d_in[5];
    const float* W_w = (const float*)d_in[6];
    const float* W_b = (const float*)d_in[7];
    const float* p1_w = (const float*)d_in[8];
    const float* p2_w = (const float*)d_in[9];
    const float* p3_w = (const float*)d_in[10];
    const float* p3_b = (const float*)d_in[11];
    float* outp = (float*)d_out;

    // ---- workspace layout (bytes) ----
    char* wsb = (char*)d_ws;
    float* Wg_w = (float*)(wsb + 0);                    //  1,048,576  fp32 512x512
    unsigned short* Whi = (unsigned short*)(wsb + 1048576);   // 1536x512 bf16
    unsigned short* Wlo = (unsigned short*)(wsb + 2621440);
    unsigned short* p1h = (unsigned short*)(wsb + 4194304);   // 512x512
    unsigned short* p1l = (unsigned short*)(wsb + 4718592);
    unsigned short* p2h = (unsigned short*)(wsb + 5242880);
    unsigned short* p2l = (unsigned short*)(wsb + 5767168);
    unsigned short* Xh  = (unsigned short*)(wsb + 6291456);   // 6144x512
    unsigned short* Xl  = (unsigned short*)(wsb + 12582912);
    unsigned short* Thh = (unsigned short*)(wsb + 18874368);  // 6144x512
    unsigned short* Thl = (unsigned short*)(wsb + 25165824);
    unsigned short* Phh = (unsigned short*)(wsb + 31457280);
    unsigned short* Phl = (unsigned short*)(wsb + 37748736);
    float* Wg = (float*)(wsb + 44040192);               // 12,582,912 fp32 6144x512
    float* D  = (float*)(wsb + 56623104);               //  9,437,184 fp32 144x128x128
    // aliases (dead-buffer reuse):
    unsigned short* Plh = (unsigned short*)(wsb + 31457280);  // over Phh (dead after gram)
    unsigned short* Pll = (unsigned short*)(wsb + 33554432);
    unsigned short* h1h = (unsigned short*)(wsb + 18874368);  // over Thh (dead after gram)
    unsigned short* h1l = (unsigned short*)(wsb + 20971520);
    float* h2 = (float*)(wsb + 23068672);                     // 4 MB, still inside Th block

    // 1. Wg_w = W_w @ g_w (fp32)
    k_gemm_nn<<<dim3(8, 8), 256, 0, stream>>>(W_w, g_w, Wg_w, 512, 512, 512);
    // 2. split weights to bf16 hi/lo (theta|phi|Wg_w stacked; p1; p2)
    k_split_w<<<dim3(256, 5), 256, 0, stream>>>(theta_w, phi_w, Wg_w, p1_w, p2_w,
                                                Whi, Wlo, p1h, p1l, p2h, p2l);
    // 3. transpose+split inputs
    k_splitx<<<dim3(16, 4, 48), dim3(32, 8), 0, stream>>>(out1, out2, out3, Xh, Xl);
    // 4. stage A: Theta/Phi (bf16 hi/lo) + Wg (fp32)
    k_ga<<<dim3(48, 12), 256, 0, stream>>>(Whi, Wlo, Xh, Xl, Thh, Thl, Phh, Phl, Wg);
    // 5. gram matrices
    k_gram2<<<dim3(144), 256, 0, stream>>>(Thh, Thl, Phh, Phl, D);
    // 6. softmax + mix + residual + pool
    k_mix<<<dim3(2048), 512, 0, stream>>>(Xh, Xl, Wg, D, W_b, Plh, Pll);
    // 7. MLP
    k_mlp<true><<<dim3(16, 4), 256, 0, stream>>>(Plh, Pll, p1h, p1l, h1h, h1l, nullptr);
    k_mlp<false><<<dim3(16, 4), 256, 0, stream>>>(h1h, h1l, p2h, p2l, nullptr, nullptr, h2);
    // 8. final projection
    k_final<<<dim3(512), 256, 0, stream>>>(h2, p3_w, p3_b, outp);
}